// Round 9
// baseline (36.334 us; speedup 1.0000x reference)
//
#include <hip/hip_runtime.h>

// Y[b,e,k,j] = sum_i X[b, ind[b,e,k], i] * W[e,i,j]
// X:[B,T,I] f32, ind:[B,E,K] int32, W:[E,I,J] f32 -> Y:[B,E,K,J] f32
#define B_ 8
#define T_ 8192
#define I_ 128
#define E_ 16
#define J_ 128
#define K_ 1024
#define ROWS 64   // k-rows per block
#define JB 64     // j-cols per block (half expert)

typedef unsigned short u16;
typedef unsigned int   u32;
typedef __attribute__((ext_vector_type(8))) short s8v;   // 8 bf16 = 4 VGPRs
typedef __attribute__((ext_vector_type(4))) float f4v;   // MFMA accumulator

__device__ __forceinline__ u16 f2bf(float f) {
    union { float f; u32 u; } v; v.f = f;
    const u32 u = v.u;
    return (u16)((u + 0x7fffu + ((u >> 16) & 1u)) >> 16);  // RNE
}

// ---- Prepass (r2 verbatim): Wt[e][j][i] = bf16(W[e][i][j]), linear ----
__global__ void convert_wt(const float* __restrict__ W, u16* __restrict__ Wt) {
    const int t  = blockIdx.x * 256 + threadIdx.x;  // 32768 threads
    const int o8 = t * 8;                           // 8 outputs along i
    const int e  = o8 >> 14;
    const int r  = o8 & 16383;
    const int j  = r >> 7;
    const int i0 = r & 127;
    const float* Wp = W + e * (I_ * J_) + j;        // column j of W[e]
    s8v o;
#pragma unroll
    for (int u = 0; u < 8; ++u)
        o[u] = (short)f2bf(Wp[(i0 + u) * J_]);
    *reinterpret_cast<s8v*>(Wt + o8) = o;
}

// ---- Main: gather + bf16 MFMA GEMM, jh-split blocks ----
// 256 threads. LDS: WsT 16KB (64 j) + Xs 16KB (64 rows) = 32KB -> 5 blocks/CU
// (20 waves/CU). Only change vs r8: block granularity (j split in half).
template<bool PRE>
__global__ __launch_bounds__(256, 5)
void gather_mfma(const float* __restrict__ X, const int* __restrict__ ind,
                 const void* __restrict__ Wsrc, float* __restrict__ Y) {
    __shared__ u16 WsT[JB * I_];     // [jl][i], swizzled byte^=((jl&7)<<4)
    __shared__ u16 Xs[ROWS * I_];    // [r][i],  swizzled byte^=((r&7)<<4)

    const int t    = threadIdx.x;
    const int wave = t >> 6;
    const int lane = t & 63;

    // XCD b-affinity swizzle: grid=4096 (%8==0, bijective). XCD x gets
    // bid 512x..512x+511 -> be in [16x,16x+16) -> exactly batch b=x.
    const int orig = blockIdx.x;
    const int bid  = (orig & 7) * 512 + (orig >> 3);
    const int kt = bid & 15;             // K_/ROWS = 16
    const int jh = (bid >> 4) & 1;       // j half
    const int be = bid >> 5;
    const int e  = be & (E_ - 1);
    const int b  = be >> 4;
    const int k0 = kt * ROWS;

    // ---- Stage WsT: 1024 16B chunks of the linear [j][i] image half ----
    if (PRE) {
        const s8v* Wg = reinterpret_cast<const s8v*>(
            (const u16*)Wsrc + (size_t)e * (I_ * J_) + (size_t)jh * (JB * I_));
#pragma unroll
        for (int u = 0; u < 4; ++u) {
            const int c  = t + 256 * u;           // chunk id 0..1023
            const int jl = c >> 4;                // local j row 0..63
            const s8v v = Wg[c];
            *reinterpret_cast<s8v*>((char*)WsT + ((c * 16) ^ ((jl & 7) << 4))) = v;
        }
    } else {
        // Fallback: transpose+convert W[e][i][jh*64+jl] inline.
        const float* We = (const float*)Wsrc + (size_t)e * (I_ * J_) + jh * JB;
#pragma unroll
        for (int u = 0; u < 8; ++u) {
            const int f4i = t + 256 * u;          // float4 id, 0..2047
            const int i   = f4i >> 4;
            const int jl0 = (f4i & 15) * 4;
            const float4 w4 = *reinterpret_cast<const float4*>(We + (size_t)i * J_ + jl0);
            const float ws[4] = {w4.x, w4.y, w4.z, w4.w};
#pragma unroll
            for (int q = 0; q < 4; ++q) {
                const int jl = jl0 + q;
                *(u16*)((char*)WsT + ((jl * 256 + i * 2) ^ ((jl & 7) << 4))) = f2bf(ws[q]);
            }
        }
    }

    // ---- Stage Xs: gather 64 rows, convert f32->bf16 (r8 verbatim) ----
    {
        const int r   = t >> 2;                   // row 0..63
        const int q   = t & 3;                    // 32-elem quarter
        const int idx = ind[(size_t)be * K_ + k0 + r];
        const float4* Xr = reinterpret_cast<const float4*>(X + ((size_t)b * T_ + idx) * I_) + q * 8;
        const int sx = (r & 7) << 4;
        char* xrow = (char*)Xs + r * 256;
#pragma unroll
        for (int u = 0; u < 4; ++u) {
            const float4 a = Xr[2 * u], c = Xr[2 * u + 1];
            s8v o;
            o[0] = (short)f2bf(a.x); o[1] = (short)f2bf(a.y);
            o[2] = (short)f2bf(a.z); o[3] = (short)f2bf(a.w);
            o[4] = (short)f2bf(c.x); o[5] = (short)f2bf(c.y);
            o[6] = (short)f2bf(c.z); o[7] = (short)f2bf(c.w);
            *reinterpret_cast<s8v*>(xrow + ((q * 64 + u * 16) ^ sx)) = o;
        }
    }
    __syncthreads();

    // ---- Compute: wave = row-quarter rq; 16 rows x 64 j-cols per wave ----
    const int rq  = wave;               // 0..3
    const int g   = lane >> 4;
    const int l15 = lane & 15;
    const int sx  = (lane & 7) << 4;

    f4v acc[4];
#pragma unroll
    for (int n = 0; n < 4; ++n)
#pragma unroll
        for (int r = 0; r < 4; ++r) acc[n][r] = 0.f;

    const char* xb = (const char*)Xs  + (size_t)(rq * 16 + l15) * 256;
    const char* wb = (const char*)WsT + (size_t)l15 * 256;
#pragma unroll
    for (int s = 0; s < 4; ++s) {
        const int off = (s * 64 + g * 16) ^ sx;
        const s8v a0 = *reinterpret_cast<const s8v*>(xb + off);
#pragma unroll
        for (int n = 0; n < 4; ++n) {
            const s8v bf = *reinterpret_cast<const s8v*>(wb + n * 16 * 256 + off);
            acc[n] = __builtin_amdgcn_mfma_f32_16x16x32_bf16(a0, bf, acc[n], 0, 0, 0);
        }
    }

    // ---- Store (C/D: col = lane&15 -> j, row = 4g+reg -> k) ----
    float* Yb = Y + ((size_t)be * K_ + k0) * J_ + jh * JB;
#pragma unroll
    for (int n = 0; n < 4; ++n) {
        const int col = n * 16 + l15;
        const int row0 = rq * 16 + g * 4;
#pragma unroll
        for (int r = 0; r < 4; ++r)
            Yb[(size_t)(row0 + r) * J_ + col] = acc[n][r];
    }
}

extern "C" void kernel_launch(void* const* d_in, const int* in_sizes, int n_in,
                              void* d_out, int out_size, void* d_ws, size_t ws_size,
                              hipStream_t stream) {
    (void)in_sizes; (void)n_in; (void)out_size;
    const float* X   = (const float*)d_in[0];
    const int*   ind = (const int*)d_in[1];
    const float* W   = (const float*)d_in[2];
    float*       Y   = (float*)d_out;

    const size_t wt_bytes = (size_t)E_ * I_ * J_ * sizeof(u16);  // 512 KB
    const int grid = B_ * E_ * 2 * (K_ / ROWS);                   // 4096

    if (ws_size >= wt_bytes && d_ws != nullptr) {
        u16* Wt = (u16*)d_ws;
        hipLaunchKernelGGL(convert_wt, dim3(E_ * I_ * J_ / (256 * 8)), dim3(256), 0, stream, W, Wt);
        hipLaunchKernelGGL((gather_mfma<true>), dim3(grid), dim3(256), 0, stream,
                           X, ind, (const void*)Wt, Y);
    } else {
        hipLaunchKernelGGL((gather_mfma<false>), dim3(grid), dim3(256), 0, stream,
                           X, ind, (const void*)W, Y);
    }
}

// Round 10
// 33.525 us; speedup vs baseline: 1.0838x; 1.0838x over previous
//
#include <hip/hip_runtime.h>

// Y[b,e,k,j] = sum_i X[b, ind[b,e,k], i] * W[e,i,j]
// X:[B,T,I] f32, ind:[B,E,K] int32, W:[E,I,J] f32 -> Y:[B,E,K,J] f32
#define B_ 8
#define T_ 8192
#define I_ 128
#define E_ 16
#define J_ 128
#define K_ 1024
#define ROWS 64   // k-rows per block

typedef unsigned short u16;
typedef unsigned int   u32;
typedef __attribute__((ext_vector_type(8))) short s8v;   // 8 bf16 = 4 VGPRs
typedef __attribute__((ext_vector_type(4))) float f4v;   // MFMA accumulator

__device__ __forceinline__ u16 f2bf(float f) {
    union { float f; u32 u; } v; v.f = f;
    const u32 u = v.u;
    return (u16)((u + 0x7fffu + ((u >> 16) & 1u)) >> 16);  // RNE, branch-free
}

// ---- Prepass: Wt[e][j][i] = bf16(W[e][i][j]) — LINEAR image ----
// 64 blocks = (e, j-quarter). Coalesced float4 reads, padded LDS transpose,
// coalesced 16B writes. Replaces r2's column-strided scalar-read prepass.
__global__ void convert_wt(const float* __restrict__ W, u16* __restrict__ Wt) {
    __shared__ float Wf[I_ * 33];        // [i][jl], jl=0..31, padded (+1 f32)
    const int bid = blockIdx.x;          // e*4 + jq
    const int e   = bid >> 2;
    const int j0  = (bid & 3) * 32;
    const int t   = threadIdx.x;
    const float* We = W + (size_t)e * (I_ * J_);
#pragma unroll
    for (int u = 0; u < 4; ++u) {
        const int f4 = t + 256 * u;      // 0..1023
        const int i  = f4 >> 3;          // 0..127
        const int c  = f4 & 7;           // float4 within the 32-col slice
        const float4 v = *reinterpret_cast<const float4*>(We + (size_t)i * J_ + j0 + c * 4);
        float* p = &Wf[i * 33 + c * 4];
        p[0] = v.x; p[1] = v.y; p[2] = v.z; p[3] = v.w;
    }
    __syncthreads();
    char* img = (char*)Wt + (size_t)e * (I_ * J_ * 2);
#pragma unroll
    for (int u2 = 0; u2 < 2; ++u2) {
        const int c  = t + 256 * u2;     // 0..511
        const int jl = c >> 4;           // local j 0..31
        const int j  = j0 + jl;
        const int i0 = (c & 15) * 8;
        s8v o;
#pragma unroll
        for (int u = 0; u < 8; ++u)
            o[u] = (short)f2bf(Wf[(i0 + u) * 33 + jl]);
        const int cimg = j * 16 + (c & 15);           // linear [j][i] chunk
        *reinterpret_cast<s8v*>(img + cimg * 16) = o; // coalesced
    }
}

// ---- Main (r8 base): gather + bf16 MFMA GEMM, XCD b-affinity swizzle ----
// 256 threads, ROWS=64. LDS: WsT 32KB + Xs 16KB = 48KB -> 3 blocks/CU.
// Changes vs r8: swapped-operand MFMA (A=W^T, B=X) + float4 Y stores.
template<bool PRE>
__global__ __launch_bounds__(256, 3)
void gather_mfma(const float* __restrict__ X, const int* __restrict__ ind,
                 const void* __restrict__ Wsrc, float* __restrict__ Y) {
    __shared__ u16 WsT[I_ * J_];
    __shared__ u16 Xs[ROWS * I_];

    const int t    = threadIdx.x;
    const int wave = t >> 6;
    const int lane = t & 63;

    // XCD b-affinity swizzle: grid=2048, 8 XCDs. XCD x gets bid 256x..256x+255
    // -> exactly batch b=x: X[b] (4MB) + W image resident in its private L2.
    const int orig = blockIdx.x;
    const int bid  = (orig & 7) * 256 + (orig >> 3);
    const int kt = bid & 15;             // K_/ROWS = 16
    const int be = bid >> 4;
    const int e  = be & (E_ - 1);
    const int b  = be >> 4;
    const int k0 = kt * ROWS;

    // ---- Stage WsT: Wt is bf16 [j][i]; swizzled ds_writes (r8 verbatim) ----
    if (PRE) {
        const s8v* Wg = reinterpret_cast<const s8v*>((const u16*)Wsrc + (size_t)e * (I_ * J_));
#pragma unroll
        for (int u = 0; u < 8; ++u) {
            const int c   = t + 256 * u;          // 16B chunk id, 0..2047
            const int row = c >> 4;               // j
            const s8v v = Wg[c];
            *reinterpret_cast<s8v*>((char*)WsT + ((c * 16) ^ ((row & 7) << 4))) = v;
        }
    } else {
        const float* We = (const float*)Wsrc + (size_t)e * (I_ * J_);
#pragma unroll
        for (int u = 0; u < 16; ++u) {
            const int f4i = t + 256 * u;          // float4 id, 0..4095
            const int i   = f4i >> 5;
            const int j0  = (f4i & 31) * 4;
            const float4 w4 = reinterpret_cast<const float4*>(We)[f4i];
            const float ws[4] = {w4.x, w4.y, w4.z, w4.w};
#pragma unroll
            for (int q = 0; q < 4; ++q) {
                const int j = j0 + q;
                *(u16*)((char*)WsT + ((j * 256 + i * 2) ^ ((j & 7) << 4))) = f2bf(ws[q]);
            }
        }
    }

    // ---- Stage Xs: gather 64 rows, convert f32->bf16 (r8 verbatim) ----
    {
        const int r   = t >> 2;                   // row 0..63
        const int q   = t & 3;                    // 32-elem quarter
        const int idx = ind[(size_t)be * K_ + k0 + r];
        const float4* Xr = reinterpret_cast<const float4*>(X + ((size_t)b * T_ + idx) * I_) + q * 8;
        const int sx = (r & 7) << 4;
        char* xrow = (char*)Xs + r * 256;
#pragma unroll
        for (int u = 0; u < 4; ++u) {
            const float4 a = Xr[2 * u], c = Xr[2 * u + 1];
            s8v o;
            o[0] = (short)f2bf(a.x); o[1] = (short)f2bf(a.y);
            o[2] = (short)f2bf(a.z); o[3] = (short)f2bf(a.w);
            o[4] = (short)f2bf(c.x); o[5] = (short)f2bf(c.y);
            o[6] = (short)f2bf(c.z); o[7] = (short)f2bf(c.w);
            *reinterpret_cast<s8v*>(xrow + ((q * 64 + u * 16) ^ sx)) = o;
        }
    }
    __syncthreads();

    // ---- Compute: wave = (k-half rh, j-half jh); 32 k-rows x 64 j-cols ----
    // SWAPPED operands: A = W^T tile (m=j), B = X tile (n=k-row).
    // Identical k-map on A and B -> exact for any true per-lane K order.
    const int rh  = wave >> 1;
    const int jh  = wave & 1;
    const int g   = lane >> 4;
    const int l15 = lane & 15;
    const int sx  = (lane & 7) << 4;

    f4v acc[2][4];
#pragma unroll
    for (int tr = 0; tr < 2; ++tr)
#pragma unroll
        for (int nj = 0; nj < 4; ++nj)
#pragma unroll
            for (int rr = 0; rr < 4; ++rr) acc[tr][nj][rr] = 0.f;

    const char* xb = (const char*)Xs  + (size_t)(rh * 32 + l15) * 256;
    const char* wb = (const char*)WsT + (size_t)(jh * 64 + l15) * 256;
#pragma unroll
    for (int s = 0; s < 4; ++s) {
        const int off = (s * 64 + g * 16) ^ sx;
        const s8v x0 = *reinterpret_cast<const s8v*>(xb + off);
        const s8v x1 = *reinterpret_cast<const s8v*>(xb + 16 * 256 + off);
#pragma unroll
        for (int nj = 0; nj < 4; ++nj) {
            const s8v wf = *reinterpret_cast<const s8v*>(wb + nj * 16 * 256 + off);
            acc[0][nj] = __builtin_amdgcn_mfma_f32_16x16x32_bf16(wf, x0, acc[0][nj], 0, 0, 0);
            acc[1][nj] = __builtin_amdgcn_mfma_f32_16x16x32_bf16(wf, x1, acc[1][nj], 0, 0, 0);
        }
    }

    // ---- Store: D col(l15)=k-row, row(4g+rr)=j -> float4 along j.
    //      Per (row,nj): lanes g=0..3 cover 64B contiguous — coalesced,
    //      4x fewer store instructions than the scalar path. ----
    float* Yb = Y + ((size_t)be * K_ + k0) * J_;
#pragma unroll
    for (int tr = 0; tr < 2; ++tr) {
        float* rowp = Yb + (size_t)(rh * 32 + tr * 16 + l15) * J_ + jh * 64 + g * 4;
#pragma unroll
        for (int nj = 0; nj < 4; ++nj)
            *reinterpret_cast<f4v*>(rowp + nj * 16) = acc[tr][nj];
    }
}

extern "C" void kernel_launch(void* const* d_in, const int* in_sizes, int n_in,
                              void* d_out, int out_size, void* d_ws, size_t ws_size,
                              hipStream_t stream) {
    (void)in_sizes; (void)n_in; (void)out_size;
    const float* X   = (const float*)d_in[0];
    const int*   ind = (const int*)d_in[1];
    const float* W   = (const float*)d_in[2];
    float*       Y   = (float*)d_out;

    const size_t wt_bytes = (size_t)E_ * I_ * J_ * sizeof(u16);  // 512 KB
    const int grid = B_ * E_ * (K_ / ROWS);                       // 2048

    if (ws_size >= wt_bytes && d_ws != nullptr) {
        u16* Wt = (u16*)d_ws;
        hipLaunchKernelGGL(convert_wt, dim3(E_ * 4), dim3(256), 0, stream, W, Wt);
        hipLaunchKernelGGL((gather_mfma<true>), dim3(grid), dim3(256), 0, stream,
                           X, ind, (const void*)Wt, Y);
    } else {
        hipLaunchKernelGGL((gather_mfma<false>), dim3(grid), dim3(256), 0, stream,
                           X, ind, (const void*)W, Y);
    }
}

// Round 11
// 30.049 us; speedup vs baseline: 1.2092x; 1.1157x over previous
//
#include <hip/hip_runtime.h>

// Y[b,e,k,j] = sum_i X[b, ind[b,e,k], i] * W[e,i,j]
// X:[B,T,I] f32, ind:[B,E,K] int32, W:[E,I,J] f32 -> Y:[B,E,K,J] f32
#define B_ 8
#define T_ 8192
#define I_ 128
#define E_ 16
#define J_ 128
#define K_ 1024
#define ROWS 64    // k-rows per tile
#define TILES 4    // k-tiles per block (persistent)

typedef unsigned short u16;
typedef unsigned int   u32;
typedef __attribute__((ext_vector_type(8))) short s8v;   // 8 bf16 = 4 VGPRs
typedef __attribute__((ext_vector_type(4))) float f4v;   // MFMA accumulator

__device__ __forceinline__ u16 f2bf(float f) {
    union { float f; u32 u; } v; v.f = f;
    const u32 u = v.u;
    return (u16)((u + 0x7fffu + ((u >> 16) & 1u)) >> 16);  // RNE, branch-free
}

// ---- Prepass (r8 verbatim): Wt[e][j][i] = bf16(W[e][i][j]) ----
__global__ void convert_wt(const float* __restrict__ W, u16* __restrict__ Wt) {
    const int t  = blockIdx.x * 256 + threadIdx.x;  // 32768 threads
    const int o8 = t * 8;                           // 8 outputs along i
    const int e  = o8 >> 14;
    const int r  = o8 & 16383;
    const int j  = r >> 7;
    const int i0 = r & 127;
    const float* Wp = W + e * (I_ * J_) + j;        // column j of W[e]
    s8v o;
#pragma unroll
    for (int u = 0; u < 8; ++u)
        o[u] = (short)f2bf(Wp[(i0 + u) * J_]);
    *reinterpret_cast<s8v*>(Wt + o8) = o;
}

// ---- Main: persistent 4-tile blocks, Xs double-buffer pipeline ----
// 256 threads. LDS: WsT 32KB + Xs 2x16KB = 64KB -> 2 blocks/CU.
// W staged ONCE per 4 tiles; per tile: issue next X loads early, compute
// current, store, then cvt+ds_write next buffer; one barrier per tile.
template<bool PRE>
__global__ __launch_bounds__(256, 2)
void gather_mfma(const float* __restrict__ X, const int* __restrict__ ind,
                 const void* __restrict__ Wsrc, float* __restrict__ Y) {
    __shared__ u16 WsT[I_ * J_];
    __shared__ u16 Xs[2][ROWS * I_];

    const int t    = threadIdx.x;
    const int wave = t >> 6;
    const int lane = t & 63;

    // XCD b-affinity swizzle: grid=512, 8 XCDs. XCD x gets bid 64x..64x+63
    // -> b = bid>>6 = x: X[b] (4MB) + W image resident in its private L2.
    const int orig = blockIdx.x;
    const int bid  = (orig & 7) * 64 + (orig >> 3);
    const int kq = bid & 3;              // k-quarter (4 tiles of 64 rows)
    const int be = bid >> 2;
    const int e  = be & (E_ - 1);
    const int b  = be >> 4;
    const int k0 = kq * (TILES * ROWS);  // 256-row range

    const int r   = t >> 2;              // gather row 0..63 (4 threads/row)
    const int q   = t & 3;               // 32-float quarter of the row
    const int sxr = (r & 7) << 4;

    // All 4 tile indices up-front (L2-hot after first pass)
    int idx[TILES];
#pragma unroll
    for (int tt = 0; tt < TILES; ++tt)
        idx[tt] = ind[(size_t)be * K_ + k0 + tt * ROWS + r];

    // ---- Stage WsT once (r8 verbatim): Wt bf16 [j][i], swizzled ds_writes ----
    if (PRE) {
        const s8v* Wg = reinterpret_cast<const s8v*>((const u16*)Wsrc + (size_t)e * (I_ * J_));
#pragma unroll
        for (int u = 0; u < 8; ++u) {
            const int c   = t + 256 * u;          // 16B chunk id, 0..2047
            const int row = c >> 4;               // j
            const s8v v = Wg[c];
            *reinterpret_cast<s8v*>((char*)WsT + ((c * 16) ^ ((row & 7) << 4))) = v;
        }
    } else {
        const float* We = (const float*)Wsrc + (size_t)e * (I_ * J_);
#pragma unroll
        for (int u = 0; u < 16; ++u) {
            const int f4i = t + 256 * u;          // float4 id, 0..4095
            const int i   = f4i >> 5;
            const int j0  = (f4i & 31) * 4;
            const float4 w4 = reinterpret_cast<const float4*>(We)[f4i];
            const float ws[4] = {w4.x, w4.y, w4.z, w4.w};
#pragma unroll
            for (int qq = 0; qq < 4; ++qq) {
                const int j = j0 + qq;
                *(u16*)((char*)WsT + ((j * 256 + i * 2) ^ ((j & 7) << 4))) = f2bf(ws[qq]);
            }
        }
    }

    float4 v[8];
    auto load_rows = [&](int idxv) {
        const float4* Xr = reinterpret_cast<const float4*>(X + ((size_t)b * T_ + idxv) * I_) + q * 8;
#pragma unroll
        for (int u = 0; u < 8; ++u) v[u] = Xr[u];
    };
    auto pack_write = [&](u16* dst) {
        char* xrow = (char*)dst + r * 256;
#pragma unroll
        for (int u = 0; u < 4; ++u) {
            const float4 a = v[2 * u], c = v[2 * u + 1];
            s8v o;
            o[0] = (short)f2bf(a.x); o[1] = (short)f2bf(a.y);
            o[2] = (short)f2bf(a.z); o[3] = (short)f2bf(a.w);
            o[4] = (short)f2bf(c.x); o[5] = (short)f2bf(c.y);
            o[6] = (short)f2bf(c.z); o[7] = (short)f2bf(c.w);
            *reinterpret_cast<s8v*>(xrow + ((q * 64 + u * 16) ^ sxr)) = o;
        }
    };

    // ---- Prologue: tile 0 into buffer 0 ----
    load_rows(idx[0]);
    pack_write(Xs[0]);
    __syncthreads();

    // ---- Compute decomposition (r8 verbatim, non-swapped) ----
    const int rh  = wave >> 1;
    const int jh  = wave & 1;
    const int g   = lane >> 4;
    const int l15 = lane & 15;
    const int sx  = (lane & 7) << 4;
    const char* wb = (const char*)WsT + (size_t)(jh * 64 + l15) * 256;

#pragma unroll
    for (int tt = 0; tt < TILES; ++tt) {
        // T14 issue-early: next tile's global loads in flight across compute
        if (tt < TILES - 1) load_rows(idx[tt + 1]);

        f4v acc[2][4];
#pragma unroll
        for (int tr = 0; tr < 2; ++tr)
#pragma unroll
            for (int n = 0; n < 4; ++n)
#pragma unroll
                for (int rr = 0; rr < 4; ++rr) acc[tr][n][rr] = 0.f;

        const char* xb = (const char*)Xs[tt & 1] + (size_t)(rh * 32 + l15) * 256;
#pragma unroll
        for (int s = 0; s < 4; ++s) {
            const int off = (s * 64 + g * 16) ^ sx;
            const s8v a0 = *reinterpret_cast<const s8v*>(xb + off);
            const s8v a1 = *reinterpret_cast<const s8v*>(xb + 16 * 256 + off);
#pragma unroll
            for (int n = 0; n < 4; ++n) {
                const s8v bf = *reinterpret_cast<const s8v*>(wb + n * 16 * 256 + off);
                acc[0][n] = __builtin_amdgcn_mfma_f32_16x16x32_bf16(a0, bf, acc[0][n], 0, 0, 0);
                acc[1][n] = __builtin_amdgcn_mfma_f32_16x16x32_bf16(a1, bf, acc[1][n], 0, 0, 0);
            }
        }

        // Store (r8 verbatim): C/D col = lane&15 -> j, row = 4g+reg -> k
        float* Yb = Y + ((size_t)be * K_ + k0 + tt * ROWS) * J_;
#pragma unroll
        for (int tr = 0; tr < 2; ++tr)
#pragma unroll
            for (int n = 0; n < 4; ++n) {
                const int col = jh * 64 + n * 16 + l15;
                const int row0 = rh * 32 + tr * 16 + g * 4;
#pragma unroll
                for (int rr = 0; rr < 4; ++rr)
                    Yb[(size_t)(row0 + rr) * J_ + col] = acc[tr][n][rr];
            }

        // Write-late into the buffer last read at iter tt-1 (drained by its barrier)
        if (tt < TILES - 1) {
            pack_write(Xs[(tt + 1) & 1]);
            __syncthreads();
        }
    }
}

extern "C" void kernel_launch(void* const* d_in, const int* in_sizes, int n_in,
                              void* d_out, int out_size, void* d_ws, size_t ws_size,
                              hipStream_t stream) {
    (void)in_sizes; (void)n_in; (void)out_size;
    const float* X   = (const float*)d_in[0];
    const int*   ind = (const int*)d_in[1];
    const float* W   = (const float*)d_in[2];
    float*       Y   = (float*)d_out;

    const size_t wt_bytes = (size_t)E_ * I_ * J_ * sizeof(u16);  // 512 KB
    const int grid = B_ * E_ * (K_ / ROWS) / TILES;               // 512

    if (ws_size >= wt_bytes && d_ws != nullptr) {
        u16* Wt = (u16*)d_ws;
        hipLaunchKernelGGL(convert_wt, dim3(E_ * I_ * J_ / (256 * 8)), dim3(256), 0, stream, W, Wt);
        hipLaunchKernelGGL((gather_mfma<true>), dim3(grid), dim3(256), 0, stream,
                           X, ind, (const void*)Wt, Y);
    } else {
        hipLaunchKernelGGL((gather_mfma<false>), dim3(grid), dim3(256), 0, stream,
                           X, ind, (const void*)W, Y);
    }
}

// Round 12
// 29.860 us; speedup vs baseline: 1.2168x; 1.0063x over previous
//
#include <hip/hip_runtime.h>

// Y[b,e,k,j] = sum_i X[b, ind[b,e,k], i] * W[e,i,j]
// X:[B,T,I] f32, ind:[B,E,K] int32, W:[E,I,J] f32 -> Y:[B,E,K,J] f32
#define B_ 8
#define T_ 8192
#define I_ 128
#define E_ 16
#define J_ 128
#define K_ 1024
#define ROWS 128   // k-rows per block (512 threads)

typedef unsigned short u16;
typedef unsigned int   u32;
typedef __attribute__((ext_vector_type(8))) short s8v;   // 8 bf16 = 4 VGPRs
typedef __attribute__((ext_vector_type(4))) float f4v;   // MFMA accumulator

__device__ __forceinline__ u16 f2bf(float f) {
    union { float f; u32 u; } v; v.f = f;
    const u32 u = v.u;
    return (u16)((u + 0x7fffu + ((u >> 16) & 1u)) >> 16);  // RNE, branch-free
}

// ---- Prepass (r8 verbatim): Wt[e][j][i] = bf16(W[e][i][j]) ----
__global__ void convert_wt(const float* __restrict__ W, u16* __restrict__ Wt) {
    const int t  = blockIdx.x * 256 + threadIdx.x;  // 32768 threads
    const int o8 = t * 8;                           // 8 outputs along i
    const int e  = o8 >> 14;
    const int r  = o8 & 16383;
    const int j  = r >> 7;
    const int i0 = r & 127;
    const float* Wp = W + e * (I_ * J_) + j;        // column j of W[e]
    s8v o;
#pragma unroll
    for (int u = 0; u < 8; ++u)
        o[u] = (short)f2bf(Wp[(i0 + u) * J_]);
    *reinterpret_cast<s8v*>(Wt + o8) = o;
}

// ---- Main: gather + bf16 MFMA GEMM, 512 threads / 128 rows ----
// LDS: WsT 32KB + Xs 32KB = 64KB -> 2 blocks/CU = 16 waves/CU.
// Per-wave compute shape identical to r8 (32 rows x 64 cols); per-output
// X staging identical; W staging halved. Non-swapped MFMA, scalar stores.
template<bool PRE>
__global__ __launch_bounds__(512, 4)
void gather_mfma(const float* __restrict__ X, const int* __restrict__ ind,
                 const void* __restrict__ Wsrc, float* __restrict__ Y) {
    __shared__ u16 WsT[I_ * J_];
    __shared__ u16 Xs[ROWS * I_];

    const int t    = threadIdx.x;
    const int wave = t >> 6;
    const int lane = t & 63;

    // XCD b-affinity swizzle: grid=1024, 8 XCDs. XCD x gets bid 128x..128x+127
    // -> be in [16x,16x+16) -> exactly batch b=x (X[b] 4MB L2-resident).
    const int orig = blockIdx.x;
    const int bid  = (orig & 7) * 128 + (orig >> 3);
    const int kt = bid & 7;              // K_/ROWS = 8
    const int be = bid >> 3;
    const int e  = be & (E_ - 1);
    const int b  = be >> 4;
    const int k0 = kt * ROWS;

    // ---- Stage WsT: Wt is bf16 [j][i]; swizzled ds_writes ----
    if (PRE) {
        const s8v* Wg = reinterpret_cast<const s8v*>((const u16*)Wsrc + (size_t)e * (I_ * J_));
#pragma unroll
        for (int u = 0; u < 4; ++u) {
            const int c   = t + 512 * u;          // 16B chunk id, 0..2047
            const int row = c >> 4;               // j
            const s8v v = Wg[c];
            *reinterpret_cast<s8v*>((char*)WsT + ((c * 16) ^ ((row & 7) << 4))) = v;
        }
    } else {
        // Fallback: transpose+convert W[e] (f32 [i][j]) inline.
        const float* We = (const float*)Wsrc + (size_t)e * (I_ * J_);
#pragma unroll
        for (int u = 0; u < 8; ++u) {
            const int f4i = t + 512 * u;          // float4 id, 0..4095
            const int i   = f4i >> 5;
            const int j0  = (f4i & 31) * 4;
            const float4 w4 = reinterpret_cast<const float4*>(We)[f4i];
            const float ws[4] = {w4.x, w4.y, w4.z, w4.w};
#pragma unroll
            for (int q = 0; q < 4; ++q) {
                const int j = j0 + q;
                *(u16*)((char*)WsT + ((j * 256 + i * 2) ^ ((j & 7) << 4))) = f2bf(ws[q]);
            }
        }
    }

    // ---- Stage Xs: gather 128 rows, convert f32->bf16 (r8 pattern) ----
    {
        const int r   = t >> 2;                   // row 0..127
        const int q   = t & 3;                    // 32-elem quarter
        const int idx = ind[(size_t)be * K_ + k0 + r];
        const float4* Xr = reinterpret_cast<const float4*>(X + ((size_t)b * T_ + idx) * I_) + q * 8;
        const int sx = (r & 7) << 4;
        char* xrow = (char*)Xs + r * 256;
#pragma unroll
        for (int u = 0; u < 4; ++u) {
            const float4 a = Xr[2 * u], c = Xr[2 * u + 1];
            s8v o;
            o[0] = (short)f2bf(a.x); o[1] = (short)f2bf(a.y);
            o[2] = (short)f2bf(a.z); o[3] = (short)f2bf(a.w);
            o[4] = (short)f2bf(c.x); o[5] = (short)f2bf(c.y);
            o[6] = (short)f2bf(c.z); o[7] = (short)f2bf(c.w);
            *reinterpret_cast<s8v*>(xrow + ((q * 64 + u * 16) ^ sx)) = o;
        }
    }
    __syncthreads();

    // ---- Compute: wave = (row-quarter rq, j-half jh); 32 rows x 64 cols ----
    const int rq  = wave >> 1;          // 0..3
    const int jh  = wave & 1;
    const int g   = lane >> 4;
    const int l15 = lane & 15;
    const int sx  = (lane & 7) << 4;

    f4v acc[2][4];
#pragma unroll
    for (int tr = 0; tr < 2; ++tr)
#pragma unroll
        for (int n = 0; n < 4; ++n)
#pragma unroll
            for (int r = 0; r < 4; ++r) acc[tr][n][r] = 0.f;

    const char* xb = (const char*)Xs  + (size_t)(rq * 32 + l15) * 256;
    const char* wb = (const char*)WsT + (size_t)(jh * 64 + l15) * 256;
#pragma unroll
    for (int s = 0; s < 4; ++s) {
        const int off = (s * 64 + g * 16) ^ sx;
        const s8v a0 = *reinterpret_cast<const s8v*>(xb + off);
        const s8v a1 = *reinterpret_cast<const s8v*>(xb + 16 * 256 + off);
#pragma unroll
        for (int n = 0; n < 4; ++n) {
            const s8v bf = *reinterpret_cast<const s8v*>(wb + n * 16 * 256 + off);
            acc[0][n] = __builtin_amdgcn_mfma_f32_16x16x32_bf16(a0, bf, acc[0][n], 0, 0, 0);
            acc[1][n] = __builtin_amdgcn_mfma_f32_16x16x32_bf16(a1, bf, acc[1][n], 0, 0, 0);
        }
    }

    // ---- Store (C/D: col = lane&15 -> j, row = 4*(lane>>4)+reg -> k) ----
    float* Yb = Y + ((size_t)be * K_ + k0) * J_;
#pragma unroll
    for (int tr = 0; tr < 2; ++tr)
#pragma unroll
        for (int n = 0; n < 4; ++n) {
            const int col = jh * 64 + n * 16 + l15;
            const int row0 = rq * 32 + tr * 16 + g * 4;
#pragma unroll
            for (int r = 0; r < 4; ++r)
                Yb[(size_t)(row0 + r) * J_ + col] = acc[tr][n][r];
        }
}

extern "C" void kernel_launch(void* const* d_in, const int* in_sizes, int n_in,
                              void* d_out, int out_size, void* d_ws, size_t ws_size,
                              hipStream_t stream) {
    (void)in_sizes; (void)n_in; (void)out_size;
    const float* X   = (const float*)d_in[0];
    const int*   ind = (const int*)d_in[1];
    const float* W   = (const float*)d_in[2];
    float*       Y   = (float*)d_out;

    const size_t wt_bytes = (size_t)E_ * I_ * J_ * sizeof(u16);  // 512 KB
    const int grid = B_ * E_ * (K_ / ROWS);                       // 1024

    if (ws_size >= wt_bytes && d_ws != nullptr) {
        u16* Wt = (u16*)d_ws;
        hipLaunchKernelGGL(convert_wt, dim3(E_ * I_ * J_ / (256 * 8)), dim3(256), 0, stream, W, Wt);
        hipLaunchKernelGGL((gather_mfma<true>), dim3(grid), dim3(512), 0, stream,
                           X, ind, (const void*)Wt, Y);
    } else {
        hipLaunchKernelGGL((gather_mfma<false>), dim3(grid), dim3(512), 0, stream,
                           X, ind, (const void*)W, Y);
    }
}